// Round 1
// baseline (196.262 us; speedup 1.0000x reference)
//
#include <hip/hip_runtime.h>
#include <math.h>

#define BATCH 128
#define NN 512
#define PARTS 8
#define INF_F 1000000000.0f
#define MU_F 1e-8f
#define SAFE_T 0.05f
// float(2*pi) = 6.2831855f ; float(2*pi/8) = 0.7853982f — match reference f32 constants
#define TWO_PI_F 6.28318530717958647692f
#define STEP_F 0.78539816339744830962f

__global__ __launch_bounds__(256) void pc_kernel(
    const float* __restrict__ seg_maps,   // (B, N, N)
    const float* __restrict__ paras,      // (B, 4): Wx, Wy, bx, by
    const float* __restrict__ traj,       // (B, 8, 2)
    const float* __restrict__ cpos,       // (B, 1, 2)
    float* __restrict__ out)              // (B, 16, 3)
{
    const int b   = blockIdx.x;
    const int tid = threadIdx.x;

    const float Wx = paras[b * 4 + 0];
    const float Wy = paras[b * 4 + 1];
    const float bx = paras[b * 4 + 2];
    const float by = paras[b * 4 + 3];
    const float cx = cpos[b * 2 + 0];
    const float cy = cpos[b * 2 + 1];

    // moving_vector = (traj[7]+c) - (traj[0]+c)  — keep the reference's op order
    const float o0x = traj[b * 16 + 0]  + cx;
    const float o0y = traj[b * 16 + 1]  + cy;
    const float o7x = traj[b * 16 + 14] + cx;
    const float o7y = traj[b * 16 + 15] + cy;
    const float mvx = o7x - o0x;
    const float mvy = o7y - o0y;
    const float ml  = __fsqrt_rn(__fadd_rn(__fmul_rn(mvx, mvx), __fmul_rn(mvy, mvy)));
    const float r   = 2.0f * ml;   // VISION_RADIUS = 2.0

    // Pixel-space bounding box of the valid disk: |((i-bx)/Wx) - cx| <= r
    // => i in [bx + Wx*(cx-r), bx + Wx*(cx+r)]  (Wx > 0). Margin +-2 px for fp slop.
    int ilo = (int)floorf(bx + Wx * (cx - r)) - 2;
    int ihi = (int)ceilf (bx + Wx * (cx + r)) + 2;
    int jlo = (int)floorf(by + Wy * (cy - r)) - 2;
    int jhi = (int)ceilf (by + Wy * (cy + r)) + 2;
    ilo = max(ilo, 0); ihi = min(ihi, NN - 1);
    jlo = max(jlo, 0); jhi = min(jhi, NN - 1);

    float mind[PARTS];
#pragma unroll
    for (int k = 0; k < PARTS; ++k) mind[k] = INF_F;

    if (ilo <= ihi && jlo <= jhi) {
        const int w     = jhi - jlo + 1;
        const int h     = ihi - ilo + 1;
        const int count = w * h;
        const float* mb = seg_maps + (size_t)b * NN * NN;

        for (int t = tid; t < count; t += 256) {
            const int i = ilo + t / w;
            const int j = jlo + t % w;

            // dvec = (pixel - b)/W - c  (pixel.x = row i, pixel.y = col j)
            const float dx = __fdiv_rn((float)i - bx, Wx) - cx;
            const float dy = __fdiv_rn((float)j - by, Wy) - cy;
            const float s  = __fadd_rn(__fmul_rn(dx, dx), __fmul_rn(dy, dy));
            const float dist = __fsqrt_rn(s);

            const float m = mb[i * NN + j];
            // valid = ~(m <= 0.05) & (dist <= r)
            if (m > SAFE_T && dist <= r) {
                const float ang = atan2f(dx, dy);
                const float am  = (ang < 0.0f) ? (ang + (float)TWO_PI_F) : ang;
                const int bin   = (int)__fdiv_rn(am, (float)STEP_F);  // trunc, matches astype(int32)
                if (bin < PARTS) {  // reference's segment_min drops bin==8 (am rounded to 2π)
                    const float ed = __fdiv_rn(dist + MU_F, m + MU_F);
                    mind[bin] = fminf(mind[bin], ed);
                }
            }
        }
    }

    // Reduce: shuffle within each 64-lane wave, then LDS across the 4 waves.
    __shared__ float red[4 * PARTS];
    const int lane = tid & 63;
    const int wave = tid >> 6;
#pragma unroll
    for (int k = 0; k < PARTS; ++k) {
        float v = mind[k];
#pragma unroll
        for (int off = 32; off >= 1; off >>= 1)
            v = fminf(v, __shfl_xor(v, off, 64));
        if (lane == 0) red[wave * PARTS + k] = v;
    }
    __syncthreads();

    // (16, 3) output per batch; rows 8..15 are the zero pad.
    if (tid < 48) {
        const int k = tid / 3;
        const int c = tid % 3;
        float val = 0.0f;
        if (k < PARTS) {
            const float mn = fminf(fminf(red[0 * PARTS + k], red[1 * PARTS + k]),
                                   fminf(red[2 * PARTS + k], red[3 * PARTS + k]));
            if (mn < INF_F) {           // obstacle
                if (c == 0)      val = ml;
                else if (c == 1) val = mn;
                else             val = __fdiv_rn(__fmul_rn((float)TWO_PI_F, (float)k + 0.5f), 8.0f);
            }
        }
        out[b * 48 + k * 3 + c] = val;
    }
}

extern "C" void kernel_launch(void* const* d_in, const int* in_sizes, int n_in,
                              void* d_out, int out_size, void* d_ws, size_t ws_size,
                              hipStream_t stream) {
    const float* seg_maps = (const float*)d_in[0];  // (128, 512, 512)
    const float* paras    = (const float*)d_in[1];  // (128, 4)
    const float* traj     = (const float*)d_in[2];  // (128, 8, 2)
    const float* cpos     = (const float*)d_in[3];  // (128, 1, 2)
    // d_in[4] = map_pos_pixel — recomputed inline, never loaded.

    pc_kernel<<<BATCH, 256, 0, stream>>>(seg_maps, paras, traj, cpos, (float*)d_out);
}